// Round 8
// baseline (80.081 us; speedup 1.0000x reference)
//
#include <hip/hip_runtime.h>

// Hausdorff adv2ori via MFMA: B=8, K=8192.
// dist(n,m) = oo_n + aa_m - 2*o.a ; C = mfma(A',B') = oo_n - 2*o.a (fp16 hi/lo split)
// loss = mean_b( w_b * max_m min_n dist )
//
// K=16 slot packing (one 32x32x16_f16 MFMA per 32x32 pair tile):
//   A'(ori n): [oh.x oh.y oh.z | oh.x oh.y oh.z | ol.x ol.y ol.z | oo_h oo_l | 0 x5]
//   B'(adv m): [bh.x bh.y bh.z | bl.x bl.y bl.z | bh.x bh.y bh.z | 1    1    | 0 x5]
//   b = -2*a; dropped ol.bl terms ~1e-6; fp32 accumulate. absmax=0 in R1-R6.
//
// R7 post-mortem: hipLaunchCooperativeKernel silently failed under the
// harness's graph capture (out==0 -> absmax == reference). Cooperative fusion
// abandoned; two-dispatch R6 structure restored.
// R8 theory: R6's single 4-MFMA asm block needs 64 earlyclobber VGPRs -> total
// liveset ~126+; with no waves/EU bound the compiler could exceed 128 VGPRs
// (occupancy 2-3 waves/SIMD) or spill to scratch — either explains main staying
// ~25us vs ~8us model, invariant across staging variants. Fixes:
//  (a) __launch_bounds__(256,4): force <=128 VGPR, exactly 4 blocks/CU.
//  (b) split asm into two 2-MFMA blocks (d0/d1 consumed before d2/d3 exist):
//      peak liveset ~94 regs -> no spills under the bound.

#define KPTS 8192
#define BATCH 8
#define NSPLIT 8                      // row slices
#define RBLK (KPTS / NSPLIT)          // 1024 rows per slice
#define TSLICE (RBLK / 32)            // 32 MFMA row-tiles per slice
#define CBLK 512                      // adv columns per block (4 waves x 128)
#define MCHUNK (KPTS / CBLK)          // 16

typedef _Float16 half8 __attribute__((ext_vector_type(8)));
typedef float f32x16 __attribute__((ext_vector_type(16)));

// min over 16 accum values folded into running min rm (min3-fusable tree)
__device__ __forceinline__ float min16acc(float rm, const f32x16 c) {
    float u0 = fminf(fminf(c[0],  c[1]),  c[2]);
    float u1 = fminf(fminf(c[3],  c[4]),  c[5]);
    float u2 = fminf(fminf(c[6],  c[7]),  c[8]);
    float u3 = fminf(fminf(c[9],  c[10]), c[11]);
    float u4 = fminf(fminf(c[12], c[13]), c[14]);
    float u5 = fminf(fminf(u0, u1), c[15]);
    float u6 = fminf(fminf(u2, u3), u4);
    return fminf(fminf(u5, u6), rm);
}

__global__ __launch_bounds__(256, 4) void hausdorff(const float* __restrict__ adv,
                                                    const float* __restrict__ ori,
                                                    float* __restrict__ part,
                                                    float* __restrict__ out) {
    // Tile-planar A' slice: tile t at halfs [t*512, (t+1)*512): lane reads
    // byte lane*16 -> linear, conflict-free. +1 pad tile for last prefetch.
    __shared__ _Float16 sA[(TSLICE + 1) * 512];   // 33 KB -> 4 blocks/CU

    const int bid  = blockIdx.x;          // grid = 8 * 16 * 8 = 1024
    const int b    = bid >> 7;
    const int mc   = (bid >> 3) & (MCHUNK - 1);
    const int ns   = bid & 7;
    const int tid  = threadIdx.x;
    const int lane = tid & 63;
    const int wv   = tid >> 6;
    const int r    = lane & 31;           // MFMA row/col index
    const int hk   = lane >> 5;           // K-half

    if (bid == 0 && tid == 0) out[0] = 0.0f;   // for reduceB's atomicAdd

    const _Float16 Z = (_Float16)0.0f, ONE = (_Float16)1.0f;

    // ---- B-fragments + aa for this wave's 4 column groups ----
    const float* advb = adv + (size_t)b * KPTS * 3;
    const int m0 = mc * CBLK + wv * 128 + r;
    half8 bf0, bf1, bf2, bf3;
    float aa0, aa1, aa2, aa3;
#pragma unroll
    for (int i = 0; i < 4; ++i) {
        const int m = m0 + 32 * i;
        float ax = advb[3 * m], ay = advb[3 * m + 1], az = advb[3 * m + 2];
        float aa = ax * ax + ay * ay + az * az;
        float tx = -2.f * ax, ty = -2.f * ay, tz = -2.f * az;
        _Float16 bx = (_Float16)tx, by = (_Float16)ty, bz = (_Float16)tz;
        _Float16 cx = (_Float16)(tx - (float)bx);
        _Float16 cy = (_Float16)(ty - (float)by);
        _Float16 cz = (_Float16)(tz - (float)bz);
        half8 h0 = {bx, by, bz, cx, cy, cz, bx, by};
        half8 h1 = {bz, ONE, ONE, Z, Z, Z, Z, Z};
        half8 bi = hk ? h1 : h0;
        if (i == 0) { bf0 = bi; aa0 = aa; }
        else if (i == 1) { bf1 = bi; aa1 = aa; }
        else if (i == 2) { bf2 = bi; aa2 = aa; }
        else { bf3 = bi; aa3 = aa; }
    }

    // ---- stage + convert this block's 1024-row slice into LDS (once) ----
    const float* orib = ori + ((size_t)b * KPTS + (size_t)ns * RBLK) * 3;
#pragma unroll
    for (int i = 0; i < 4; ++i) {
        const int rr = tid + i * 256;
        const float* op = orib + (size_t)rr * 3;
        float x = op[0], y = op[1], z = op[2];
        float oo = x * x + y * y + z * z;
        _Float16 hx = (_Float16)x, hy = (_Float16)y, hz = (_Float16)z;
        _Float16 lx = (_Float16)(x - (float)hx);
        _Float16 ly = (_Float16)(y - (float)hy);
        _Float16 lz = (_Float16)(z - (float)hz);
        _Float16 oh = (_Float16)oo;
        _Float16 ol = (_Float16)(oo - (float)oh);
        half8 a0 = {hx, hy, hz, hx, hy, hz, lx, ly};
        half8 a1 = {lz, oh, ol, Z, Z, Z, Z, Z};
        const int off = ((rr >> 5) << 9) + ((rr & 31) << 3);
        *(half8*)(&sA[off])       = a0;
        *(half8*)(&sA[off + 256]) = a1;
    }
    __syncthreads();   // the only barrier

    f32x16 zc;
#pragma unroll
    for (int i = 0; i < 16; ++i) zc[i] = 0.0f;

    float rm0 = __builtin_huge_valf(), rm1 = __builtin_huge_valf();
    float rm2 = __builtin_huge_valf(), rm3 = __builtin_huge_valf();

    const _Float16* apl = sA + lane * 8;   // lane's 16B within tile 0
    half8 af = *(const half8*)apl;

#pragma unroll 2
    for (int t = 0; t < TSLICE; ++t) {
        half8 afn = *(const half8*)(apl + (size_t)(t + 1) * 512);  // prefetch (pad tile at t=31)

        // VGPR-form MFMA, 2 at a time: halves earlyclobber pressure (32 regs
        // live, reused for d2/d3). 3x s_nop 7 = 24 wait states >= ~17 needed
        // for 16-pass MFMA -> VALU read.
        f32x16 d0, d1;
        asm("v_mfma_f32_32x32x16_f16 %0, %2, %3, %5\n\t"
            "v_mfma_f32_32x32x16_f16 %1, %2, %4, %5\n\t"
            "s_nop 7\n\ts_nop 7\n\ts_nop 7"
            : "=&v"(d0), "=&v"(d1)
            : "v"(af), "v"(bf0), "v"(bf1), "v"(zc));
        rm0 = min16acc(rm0, d0);
        rm1 = min16acc(rm1, d1);

        f32x16 d2, d3;
        asm("v_mfma_f32_32x32x16_f16 %0, %2, %3, %5\n\t"
            "v_mfma_f32_32x32x16_f16 %1, %2, %4, %5\n\t"
            "s_nop 7\n\ts_nop 7\n\ts_nop 7"
            : "=&v"(d2), "=&v"(d3)
            : "v"(af), "v"(bf2), "v"(bf3), "v"(zc));
        rm2 = min16acc(rm2, d2);
        rm3 = min16acc(rm3, d3);

        af = afn;
    }

    // complete the 32-row min (lanes l, l^32 cover complementary rows, same col)
    rm0 = fminf(rm0, __shfl_xor(rm0, 32, 64));
    rm1 = fminf(rm1, __shfl_xor(rm1, 32, 64));
    rm2 = fminf(rm2, __shfl_xor(rm2, 32, 64));
    rm3 = fminf(rm3, __shfl_xor(rm3, 32, 64));

    // plain coalesced partial stores part[ns][b][col] (no init required)
    float* p = part + ((size_t)ns * BATCH + b) * KPTS;
    if (hk == 0) {
        p[m0]      = fmaxf(rm0 + aa0, 0.0f);
        p[m0 + 32] = fmaxf(rm1 + aa1, 0.0f);
        p[m0 + 64] = fmaxf(rm2 + aa2, 0.0f);
        p[m0 + 96] = fmaxf(rm3 + aa3, 0.0f);
    }
}

// 8 blocks (one per batch), 1024 threads: min over slices, max over columns.
__global__ __launch_bounds__(1024) void reduceB(const float* __restrict__ part,
                                                const float* __restrict__ w,
                                                float* __restrict__ out) {
    const int b = blockIdx.x;
    const int tid = threadIdx.x;

    float mx = 0.0f;   // partials are clamped nonneg
#pragma unroll
    for (int h = 0; h < 2; ++h) {
        const int c4 = tid + h * 1024;       // float4 index, 2048 per row
        float4 v[NSPLIT];
#pragma unroll
        for (int s = 0; s < NSPLIT; ++s)
            v[s] = *(const float4*)(part + ((size_t)s * BATCH + b) * KPTS + (size_t)c4 * 4);
        float4 mn = v[0];
#pragma unroll
        for (int s = 1; s < NSPLIT; ++s) {
            mn.x = fminf(mn.x, v[s].x); mn.y = fminf(mn.y, v[s].y);
            mn.z = fminf(mn.z, v[s].z); mn.w = fminf(mn.w, v[s].w);
        }
        mx = fmaxf(mx, fmaxf(fmaxf(mn.x, mn.y), fmaxf(mn.z, mn.w)));
    }

#pragma unroll
    for (int off = 32; off; off >>= 1)
        mx = fmaxf(mx, __shfl_xor(mx, off, 64));

    __shared__ float red[16];
    if ((tid & 63) == 0) red[tid >> 6] = mx;
    __syncthreads();
    if (tid == 0) {
        float m2 = red[0];
#pragma unroll
        for (int i = 1; i < 16; ++i) m2 = fmaxf(m2, red[i]);
        atomicAdd(out, m2 * w[b] * (1.0f / BATCH));
    }
}

extern "C" void kernel_launch(void* const* d_in, const int* in_sizes, int n_in,
                              void* d_out, int out_size, void* d_ws, size_t ws_size,
                              hipStream_t stream) {
    const float* adv = (const float*)d_in[0];   // [B, K, 3]
    const float* ori = (const float*)d_in[1];   // [B, K, 3]
    const float* w   = (const float*)d_in[2];   // [B]
    float* out = (float*)d_out;
    float* part = (float*)d_ws;                 // NSPLIT*B*K floats = 2 MB

    hausdorff<<<BATCH * MCHUNK * NSPLIT, 256, 0, stream>>>(adv, ori, part, out);
    reduceB<<<BATCH, 1024, 0, stream>>>((const float*)part, w, out);
}